// Round 7
// baseline (1909.958 us; speedup 1.0000x reference)
//
#include <hip/hip_runtime.h>
#include <cstdint>
#include <cstddef>

typedef _Float16 f16;
typedef _Float16 f16x2 __attribute__((ext_vector_type(2)));
typedef _Float16 f16x8 __attribute__((ext_vector_type(8)));
typedef float f32x4 __attribute__((ext_vector_type(4)));

#define NB_TOT   2048
#define F0_      39
#define DDIM     32
#define HROW     104            // padded hidden row (f16), 208B, 16B-aligned rows
#define HBATCH   (DDIM*HROW)    // 3328 f16 per batch
// slab: [step][mt(14)][lane(64)][j(8)] f16 -> 7168 f16 = 14336 B per step, contiguous
#define SLAB_F16S 7168
#define SLAB_BYTES 14336
#define SLAB_CHUNKS 896         // 16B chunks per step

// workspace layout (bytes)
#define SZ_H     ((size_t)NB_TOT*HBATCH*2)
#define OFF_H0   ((size_t)0)
#define OFF_H1   (OFF_H0 + SZ_H)
#define OFF_H2   (OFF_H1 + SZ_H)
#define OFF_W0   (OFF_H2 + SZ_H)
#define SZ_W0    ((size_t)50*SLAB_BYTES)
#define OFF_W1   (OFF_W0 + SZ_W0)
#define SZ_W12   ((size_t)130*SLAB_BYTES)
#define OFF_W2   (OFF_W1 + SZ_W12)
#define OFF_BIAS (OFF_W2 + SZ_W12)

// ---------------- prep kernels ----------------

// h0[b][d][n] = (n<39) ? x[b][n][d] : 0   (fp16, transposed, zero-padded)
__global__ void k_prep_h0(const float* __restrict__ x, f16* __restrict__ h0) {
    long idx = (long)blockIdx.x * 256 + threadIdx.x;
    if (idx >= (long)NB_TOT * HBATCH) return;
    int n = (int)(idx % HROW);
    long t = idx / HROW;
    int d = (int)(t % DDIM);
    long b = t / DDIM;
    float v = 0.f;
    if (n < F0_) v = x[(b * F0_ + n) * DDIM + d];
    h0[idx] = (f16)v;
}

// slab[step][mt(14)][lane][j] = W[m*hn+n][o]
//   lane = quad*16+d0; o = mt*16+d0; m = (step%10)*4+quad; n = (step/10)*8+j
// zeros where o>=200 | m>=39 | n>=hn
__global__ void k_prep_w(const float* __restrict__ W, f16* __restrict__ slab,
                         int nsteps, int hn) {
    long idx = (long)blockIdx.x * 256 + threadIdx.x;
    if (idx >= (long)nsteps * SLAB_F16S) return;
    int e = (int)(idx % SLAB_F16S);
    int step = (int)(idx / SLAB_F16S);
    int j = e & 7;
    int lane = (e >> 3) & 63;
    int mt = e >> 9;
    int quad = lane >> 4, d0 = lane & 15;
    int o = mt * 16 + d0;
    int m = (step % 10) * 4 + quad;
    int n = (step / 10) * 8 + j;
    float v = 0.f;
    if (o < 200 && m < F0_ && n < hn)
        v = W[((long)m * hn + n) * 200 + o];
    slab[idx] = (f16)v;
}

// bias padded to 224 per layer (pad tiles read zeros)
__global__ void k_prep_bias(const float* __restrict__ b0, const float* __restrict__ b1,
                            const float* __restrict__ b2, float* __restrict__ dst) {
    int idx = blockIdx.x * 256 + threadIdx.x;
    if (idx >= 3 * 224) return;
    int L = idx / 224, o = idx % 224;
    const float* s = (L == 0) ? b0 : (L == 1 ? b1 : b2);
    dst[idx] = (o < 200) ? s[o] : 0.f;
}

// ---------------- main layer kernel ----------------

__device__ __forceinline__ void gl_lds16(const void* g, void* l) {
    __builtin_amdgcn_global_load_lds(
        (const __attribute__((address_space(1))) unsigned int*)g,
        (__attribute__((address_space(3))) unsigned int*)l,
        16, 0, 0);
}

// one step-slab = 896 x 16B chunks; 128 threads x exactly 7 loads
__device__ __forceinline__ void stage_slab(const f16* __restrict__ g, f16* l, int tid) {
#pragma unroll
    for (int rr = 0; rr < 7; ++rr) {
        int c = rr * 128 + tid;
        gl_lds16((const char*)g + (size_t)c * 16, (char*)l + (size_t)c * 16);
    }
}

// 2 waves/block, ONE batch-pair per block (1024 blocks -> 4 independent barrier
// domains per CU). Wave = M-half (mt 0-6 / 7-13). K-order nrun-major; x preloaded
// to registers once; h from global once per nr. Round-3's proven dbuf+syncthreads.
template <int NR>
__global__ __launch_bounds__(128, 2) void k_layer(
    const f16* __restrict__ xg,     // transposed x (= h0 buffer), [2048][32][104]
    const f16* __restrict__ hg,     // hidden input, same layout
    const f16* __restrict__ slabg,  // [NR*10][7168] f16, permuted layout
    const float* __restrict__ biasg,// [224], zero-padded
    f16* __restrict__ houtg,        // next hidden (or nullptr)
    float* __restrict__ outg,       // d_out [2048][400]
    int direct_lo, int outbase) {
    constexpr int NSTEPS = NR * 10;
    __shared__ __align__(16) f16 ring[2][SLAB_F16S];   // 28672 B (only LDS)

    const int tid = threadIdx.x;
    const int half = tid >> 6;       // wave = M-half
    const int lane = tid & 63;
    const int b0i = blockIdx.x * 2;  // this block's batch pair
    const int quad = lane >> 4;
    const int d0 = lane & 15;
    const int mtbase = half * 7;     // 0 or 7

    // preload ALL x scalars this lane ever needs: xr[b][mg] = {d-half0, d-half1}
    const f16* xrow0 = xg + (size_t)(b0i + 0) * HBATCH;
    const f16* xrow1 = xg + (size_t)(b0i + 1) * HBATCH;
    f16x2 xr0[10], xr1[10];          // 20 VGPRs
#pragma unroll
    for (int mg = 0; mg < 10; ++mg) {
        int m = mg * 4 + quad;       // m=39 is the zero pad row
        xr0[mg][0] = xrow0[d0 * HROW + m];
        xr0[mg][1] = xrow0[(d0 + 16) * HROW + m];
        xr1[mg][0] = xrow1[d0 * HROW + m];
        xr1[mg][1] = xrow1[(d0 + 16) * HROW + m];
    }

    stage_slab(slabg, &ring[0][0], tid);

    f32x4 acc[7][2][2];              // [mt][d-half][batch] = 112 regs (acc file)
#pragma unroll
    for (int mt = 0; mt < 7; ++mt)
#pragma unroll
        for (int nt = 0; nt < 2; ++nt)
#pragma unroll
            for (int bb = 0; bb < 2; ++bb)
                acc[mt][nt][bb] = (f32x4)0.f;

    const f16* hrow0 = hg + (size_t)(b0i + 0) * HBATCH;
    const f16* hrow1 = hg + (size_t)(b0i + 1) * HBATCH;

    __syncthreads();   // stage(0) landed (implicit vmcnt(0) drain)

    for (int nr = 0; nr < NR; ++nr) {
        // h fragments for this nrun from global (L2-resident, compiler-managed waits)
        f16x8 h00 = *(const f16x8*)&hrow0[d0 * HROW + nr * 8];
        f16x8 h01 = *(const f16x8*)&hrow0[(d0 + 16) * HROW + nr * 8];
        f16x8 h10 = *(const f16x8*)&hrow1[d0 * HROW + nr * 8];
        f16x8 h11 = *(const f16x8*)&hrow1[(d0 + 16) * HROW + nr * 8];

#pragma unroll
        for (int mg = 0; mg < 10; ++mg) {
            const int s = nr * 10 + mg;
            // stage next step into the other buffer (overlaps with compute below)
            if (s + 1 < NSTEPS)
                stage_slab(slabg + (size_t)(s + 1) * SLAB_F16S,
                           &ring[(mg + 1) & 1][0], tid);

            // B fragments: Z[k][d] = x[d,m]*h[d,n];  k = quad*8+j
            f16x8 b00 = h00 * xr0[mg][0];
            f16x8 b01 = h01 * xr0[mg][1];
            f16x8 b10 = h10 * xr1[mg][0];
            f16x8 b11 = h11 * xr1[mg][1];

            const f16* abase = &ring[mg & 1][(size_t)mtbase * 512 + lane * 8];
#pragma unroll
            for (int mt = 0; mt < 7; ++mt) {
                f16x8 a = *(const f16x8*)(abase + mt * 512);   // linear: 0 conflicts
                acc[mt][0][0] = __builtin_amdgcn_mfma_f32_16x16x32_f16(a, b00, acc[mt][0][0], 0, 0, 0);
                acc[mt][1][0] = __builtin_amdgcn_mfma_f32_16x16x32_f16(a, b01, acc[mt][1][0], 0, 0, 0);
                acc[mt][0][1] = __builtin_amdgcn_mfma_f32_16x16x32_f16(a, b10, acc[mt][0][1], 0, 0, 0);
                acc[mt][1][1] = __builtin_amdgcn_mfma_f32_16x16x32_f16(a, b11, acc[mt][1][1], 0, 0, 0);
            }
            __syncthreads();   // stage(s+1) landed; all reads of ring[mg&1] done
        }
    }

    // -------- epilogue (ring becomes scratch; post-loop barrier already passed) --------
    const bool wrh = (houtg != nullptr);
    f16* sc = (f16*)ring;            // [2 batches][32 d][104] f16 = 13312 B <= 28672
    if (wrh && half == 0) {
        unsigned int* sz = (unsigned int*)sc;
        for (int i = lane; i < HBATCH; i += 64) sz[i] = 0u;   // zero 2*HBATCH f16
    }

#pragma unroll
    for (int mt = 0; mt < 7; ++mt) {
#pragma unroll
        for (int bb = 0; bb < 2; ++bb) {
            float v[2][4];
#pragma unroll
            for (int nt = 0; nt < 2; ++nt)
#pragma unroll
                for (int i = 0; i < 4; ++i) {
                    int o = (mtbase + mt) * 16 + quad * 4 + i;
                    float t = acc[mt][nt][bb][i] + biasg[o];
                    v[nt][i] = t > 0.f ? t : 0.f;
                }
            if (wrh && half == 0) {  // hidden rows o<100 all live in half 0
#pragma unroll
                for (int nt = 0; nt < 2; ++nt)
#pragma unroll
                    for (int i = 0; i < 4; ++i) {
                        int o = mt * 16 + quad * 4 + i;
                        if (o < 100)
                            sc[bb * HBATCH + (d0 + 16 * nt) * HROW + o] = (f16)v[nt][i];
                    }
            }
            float s[4];
#pragma unroll
            for (int i = 0; i < 4; ++i) s[i] = v[0][i] + v[1][i];
#pragma unroll
            for (int mask = 1; mask <= 8; mask <<= 1)
#pragma unroll
                for (int i = 0; i < 4; ++i) s[i] += __shfl_xor(s[i], mask, 64);
            if (d0 == 0) {
#pragma unroll
                for (int i = 0; i < 4; ++i) {
                    int o = (mtbase + mt) * 16 + quad * 4 + i;
                    if (o >= direct_lo && o < 200)
                        outg[(size_t)(b0i + bb) * 400 + outbase + (o - direct_lo)] = s[i];
                }
            }
        }
    }

    if (wrh && half == 0) {
        // copy this pair's 2 transposed hidden batches to global (coalesced u32)
        const unsigned int* s2 = (const unsigned int*)sc;
        unsigned int* dg = (unsigned int*)(houtg + (size_t)b0i * HBATCH);
        for (int i = lane; i < HBATCH; i += 64) dg[i] = s2[i];
    }
}

// ---------------- launch ----------------

extern "C" void kernel_launch(void* const* d_in, const int* in_sizes, int n_in,
                              void* d_out, int out_size, void* d_ws, size_t ws_size,
                              hipStream_t stream) {
    const float* x  = (const float*)d_in[0];
    const float* W0 = (const float*)d_in[1];
    const float* b0 = (const float*)d_in[2];
    const float* W1 = (const float*)d_in[3];
    const float* b1 = (const float*)d_in[4];
    const float* W2 = (const float*)d_in[5];
    const float* b2 = (const float*)d_in[6];
    float* out = (float*)d_out;
    char* ws = (char*)d_ws;

    f16* h0 = (f16*)(ws + OFF_H0);
    f16* h1 = (f16*)(ws + OFF_H1);
    f16* h2 = (f16*)(ws + OFF_H2);
    f16* w0s = (f16*)(ws + OFF_W0);
    f16* w1s = (f16*)(ws + OFF_W1);
    f16* w2s = (f16*)(ws + OFF_W2);
    float* biasws = (float*)(ws + OFF_BIAS);

    {
        long tot = (long)NB_TOT * HBATCH;
        k_prep_h0<<<(unsigned)((tot + 255) / 256), 256, 0, stream>>>(x, h0);
    }
    k_prep_w<<<(unsigned)(((long)50 * SLAB_F16S + 255) / 256), 256, 0, stream>>>(W0, w0s, 50, 39);
    k_prep_w<<<(unsigned)(((long)130 * SLAB_F16S + 255) / 256), 256, 0, stream>>>(W1, w1s, 130, 100);
    k_prep_w<<<(unsigned)(((long)130 * SLAB_F16S + 255) / 256), 256, 0, stream>>>(W2, w2s, 130, 100);
    k_prep_bias<<<3, 256, 0, stream>>>(b0, b1, b2, biasws);

    // layer 0: hidden=x (hn=39, NR=5); direct = cur[100:200] -> out[:,0:100)
    k_layer<5><<<1024, 128, 0, stream>>>(h0, h0, w0s, biasws + 0, h1, out, 100, 0);
    // layer 1: hn=100, NR=13; direct = cur[100:200] -> out[:,100:200)
    k_layer<13><<<1024, 128, 0, stream>>>(h0, h1, w1s, biasws + 224, h2, out, 100, 100);
    // layer 2: hn=100, NR=13; direct = full cur -> out[:,200:400)
    k_layer<13><<<1024, 128, 0, stream>>>(h0, h2, w2s, biasws + 448, (f16*)nullptr, out, 0, 200);
}

// Round 8
// 355.145 us; speedup vs baseline: 5.3780x; 5.3780x over previous
//
#include <hip/hip_runtime.h>
#include <cstdint>
#include <cstddef>

typedef _Float16 f16;
typedef _Float16 f16x8 __attribute__((ext_vector_type(8)));
typedef float f32x4 __attribute__((ext_vector_type(4)));

#define NB_TOT   2048
#define F0_      39
#define DDIM     32
#define HROW     104            // padded hidden row (f16), 208B, 16B-aligned rows
#define HBATCH   (DDIM*HROW)    // 3328 f16 per batch
// slab: [step][mt(13)][lane(64)][j(8)] f16 -> 6656 f16 = 13312 B per step
#define SLAB_F16S 6656
#define SLAB_BYTES 13312
#define SLAB_CHUNKS 832         // 16B chunks per step

// workspace layout (bytes)
#define SZ_H     ((size_t)NB_TOT*HBATCH*2)
#define OFF_H0   ((size_t)0)
#define OFF_H1   (OFF_H0 + SZ_H)
#define OFF_H2   (OFF_H1 + SZ_H)
#define OFF_W0   (OFF_H2 + SZ_H)
#define SZ_W0    ((size_t)49*SLAB_BYTES)
#define OFF_W1   (OFF_W0 + SZ_W0)
#define SZ_W12   ((size_t)127*SLAB_BYTES)
#define OFF_W2   (OFF_W1 + SZ_W12)
#define OFF_BIAS (OFF_W2 + SZ_W12)

// ---------------- prep kernels ----------------

// h0[b][d][n] = (n<39) ? x[b][n][d] : 0   (fp16, transposed, zero-padded)
__global__ void k_prep_h0(const float* __restrict__ x, f16* __restrict__ h0) {
    long idx = (long)blockIdx.x * 256 + threadIdx.x;
    if (idx >= (long)NB_TOT * HBATCH) return;
    int n = (int)(idx % HROW);
    long t = idx / HROW;
    int d = (int)(t % DDIM);
    long b = t / DDIM;
    float v = 0.f;
    if (n < F0_) v = x[(b * F0_ + n) * DDIM + d];
    h0[idx] = (f16)v;
}

// slab[step][mt(13)][lane][j] = W[m*hn+n][o]   (R3's m-major k-order, linear layout)
//   lane = quad*16+d0; o = mt*16+d0; r = step*4+quad; m = r/runs; n = (r%runs)*8+j
// zeros where o>=200 | m>=39 | n>=hn
__global__ void k_prep_w(const float* __restrict__ W, f16* __restrict__ slab,
                         int nsteps, int runs, int hn) {
    long idx = (long)blockIdx.x * 256 + threadIdx.x;
    if (idx >= (long)nsteps * SLAB_F16S) return;
    int e = (int)(idx % SLAB_F16S);
    int step = (int)(idx / SLAB_F16S);
    int j = e & 7;
    int lane = (e >> 3) & 63;
    int mt = e >> 9;
    int quad = lane >> 4, d0 = lane & 15;
    int o = mt * 16 + d0;
    int r = step * 4 + quad;
    int m = r / runs;
    int n = (r - m * runs) * 8 + j;
    float v = 0.f;
    if (o < 200 && m < F0_ && n < hn)
        v = W[((long)m * hn + n) * 200 + o];
    slab[idx] = (f16)v;
}

__global__ void k_prep_bias(const float* __restrict__ b0, const float* __restrict__ b1,
                            const float* __restrict__ b2, float* __restrict__ dst) {
    int idx = blockIdx.x * 256 + threadIdx.x;
    if (idx >= 3 * 208) return;
    int L = idx / 208, o = idx % 208;
    const float* s = (L == 0) ? b0 : (L == 1 ? b1 : b2);
    dst[idx] = (o < 200) ? s[o] : 0.f;
}

// ---------------- main layer kernel ----------------

__device__ __forceinline__ void gl_lds16(const void* g, void* l) {
    __builtin_amdgcn_global_load_lds(
        (const __attribute__((address_space(1))) unsigned int*)g,
        (__attribute__((address_space(3))) unsigned int*)l,
        16, 0, 0);
}

// one step-slab = 832 x 16B chunks; 128 threads: 6 full rounds + 64-chunk tail
__device__ __forceinline__ void stage_slab(const f16* __restrict__ g, f16* l, int tid) {
#pragma unroll
    for (int rr = 0; rr < 6; ++rr) {
        int c = rr * 128 + tid;
        gl_lds16((const char*)g + (size_t)c * 16, (char*)l + (size_t)c * 16);
    }
    if (tid < 64) {
        int c = 768 + tid;
        gl_lds16((const char*)g + (size_t)c * 16, (char*)l + (size_t)c * 16);
    }
}

// 2 waves/block (wave = M-half: mt 0-6 / 7-12), ONE batch-pair per block.
// 1024 blocks -> 4 blocks/CU = 4 independent barrier domains (de-phasing).
// R3's register-safe body: runtime step loop, per-step x prefetch, h from LDS.
template <int RUNS>
__global__ __launch_bounds__(128, 2) void k_layer(
    const f16* __restrict__ xg,     // transposed x (= h0 buffer), [2048][32][104]
    const f16* __restrict__ hg,     // hidden input, same layout
    const f16* __restrict__ slabg,  // [nsteps][6656] f16, linear layout
    const float* __restrict__ biasg,// [208], zero-padded
    f16* __restrict__ houtg,        // next hidden (or nullptr)
    float* __restrict__ outg,       // d_out [2048][400]
    int nsteps, int direct_lo, int outbase) {
    __shared__ __align__(16) f16 ring[2][SLAB_F16S];   // 26624 B
    __shared__ __align__(16) f16 hl[2][HBATCH];        // 13312 B  (39936 total)

    const int tid = threadIdx.x;
    const int half = tid >> 6;       // wave = M-half
    const int lane = tid & 63;
    const int b0i = blockIdx.x * 2;  // this block's batch pair
    const int quad = lane >> 4;
    const int d0 = lane & 15;
    const int mtbase = half * 7;     // 0 or 7
    const int nmt = half ? 6 : 7;    // 7 + 6 = 13 tiles

    // stage hidden: wave w copies batch w (coalesced u32 copy)
    {
        const unsigned int* src = (const unsigned int*)(hg + (size_t)(b0i + half) * HBATCH);
        unsigned int* dst = (unsigned int*)&hl[half][0];
        for (int i = lane; i < HBATCH / 2; i += 64) dst[i] = src[i];
    }
    stage_slab(slabg, &ring[0][0], tid);

    f32x4 acc[7][2][2];              // [mt][d-half][batch] -> acc file (112)
#pragma unroll
    for (int mt = 0; mt < 7; ++mt)
#pragma unroll
        for (int nt = 0; nt < 2; ++nt)
#pragma unroll
            for (int bb = 0; bb < 2; ++bb)
                acc[mt][nt][bb] = (f32x4)0.f;

    const f16* xrow0 = xg + (size_t)(b0i + 0) * HBATCH;
    const f16* xrow1 = xg + (size_t)(b0i + 1) * HBATCH;
    const f16* hl0 = &hl[0][0];
    const f16* hl1 = &hl[1][0];

    // software-pipelined x loads for step 0 (transient; runtime loop keeps liveness low)
    int r = quad;
    int m = r / RUNS;
    int nb = (r - m * RUNS) * 8;
    f16 xa0 = xrow0[d0 * HROW + m];
    f16 xb0 = xrow0[(d0 + 16) * HROW + m];
    f16 xa1 = xrow1[d0 * HROW + m];
    f16 xb1 = xrow1[(d0 + 16) * HROW + m];

    __syncthreads();   // hl staged + slab(0) landed

    for (int step = 0; step < nsteps; ++step) {
        const int buf = step & 1;
        const bool more = (step + 1 < nsteps);
        if (more) stage_slab(slabg + (size_t)(step + 1) * SLAB_F16S,
                             &ring[buf ^ 1][0], tid);

        // prefetch next step's x scalars (latency hidden under MFMAs)
        int r2 = r + 4;
        int m2 = r2 / RUNS;
        int nb2 = (r2 - m2 * RUNS) * 8;
        f16 xa0n = (f16)0.f, xb0n = (f16)0.f, xa1n = (f16)0.f, xb1n = (f16)0.f;
        if (more) {
            xa0n = xrow0[d0 * HROW + m2];
            xb0n = xrow0[(d0 + 16) * HROW + m2];
            xa1n = xrow1[d0 * HROW + m2];
            xb1n = xrow1[(d0 + 16) * HROW + m2];
        }

        // B fragments: Z[k][d] = x[d,m]*h[d,n];  k = quad*8+j
        f16x8 h00 = *(const f16x8*)&hl0[d0 * HROW + nb];
        f16x8 h01 = *(const f16x8*)&hl0[(d0 + 16) * HROW + nb];
        f16x8 h10 = *(const f16x8*)&hl1[d0 * HROW + nb];
        f16x8 h11 = *(const f16x8*)&hl1[(d0 + 16) * HROW + nb];
        f16x8 b00 = h00 * xa0;
        f16x8 b01 = h01 * xb0;
        f16x8 b10 = h10 * xa1;
        f16x8 b11 = h11 * xb1;

        const f16* abase = &ring[buf][(size_t)mtbase * 512 + lane * 8];
#pragma unroll
        for (int mt = 0; mt < 7; ++mt) {
            if (mt < nmt) {   // wave-uniform scalar branch
                f16x8 a = *(const f16x8*)(abase + mt * 512);   // linear: 0 conflicts
                acc[mt][0][0] = __builtin_amdgcn_mfma_f32_16x16x32_f16(a, b00, acc[mt][0][0], 0, 0, 0);
                acc[mt][1][0] = __builtin_amdgcn_mfma_f32_16x16x32_f16(a, b01, acc[mt][1][0], 0, 0, 0);
                acc[mt][0][1] = __builtin_amdgcn_mfma_f32_16x16x32_f16(a, b10, acc[mt][0][1], 0, 0, 0);
                acc[mt][1][1] = __builtin_amdgcn_mfma_f32_16x16x32_f16(a, b11, acc[mt][1][1], 0, 0, 0);
            }
        }

        r = r2; m = m2; nb = nb2;
        xa0 = xa0n; xb0 = xb0n; xa1 = xa1n; xb1 = xb1n;
        __syncthreads();   // stage(s+1) landed; all reads of ring[buf] done
    }

    // -------- epilogue (ring becomes scratch) --------
    const bool wrh = (houtg != nullptr);
    f16* sc = (f16*)ring;            // [2 batches][32 d][104] = 13312 B <= 26624
    if (wrh && half == 0) {          // hidden rows o<100 all live in half 0
        unsigned int* sz = (unsigned int*)sc;
        for (int i = lane; i < HBATCH; i += 64) sz[i] = 0u;   // zero 2*HBATCH f16
    }

#pragma unroll
    for (int mt = 0; mt < 7; ++mt) {
        if (mt < nmt) {
#pragma unroll
            for (int bb = 0; bb < 2; ++bb) {
                float v[2][4];
#pragma unroll
                for (int nt = 0; nt < 2; ++nt)
#pragma unroll
                    for (int i = 0; i < 4; ++i) {
                        int o = (mtbase + mt) * 16 + quad * 4 + i;
                        float t = acc[mt][nt][bb][i] + biasg[o];
                        v[nt][i] = t > 0.f ? t : 0.f;
                    }
                if (wrh && half == 0) {
#pragma unroll
                    for (int nt = 0; nt < 2; ++nt)
#pragma unroll
                        for (int i = 0; i < 4; ++i) {
                            int o = mt * 16 + quad * 4 + i;
                            if (o < 100)
                                sc[bb * HBATCH + (d0 + 16 * nt) * HROW + o] = (f16)v[nt][i];
                        }
                }
                float s[4];
#pragma unroll
                for (int i = 0; i < 4; ++i) s[i] = v[0][i] + v[1][i];
#pragma unroll
                for (int mask = 1; mask <= 8; mask <<= 1)
#pragma unroll
                    for (int i = 0; i < 4; ++i) s[i] += __shfl_xor(s[i], mask, 64);
                if (d0 == 0) {
#pragma unroll
                    for (int i = 0; i < 4; ++i) {
                        int o = (mtbase + mt) * 16 + quad * 4 + i;
                        if (o >= direct_lo && o < 200)
                            outg[(size_t)(b0i + bb) * 400 + outbase + (o - direct_lo)] = s[i];
                    }
                }
            }
        }
    }

    if (wrh && half == 0) {
        // copy this pair's 2 transposed hidden batches to global (coalesced u32)
        const unsigned int* s2 = (const unsigned int*)sc;
        unsigned int* dg = (unsigned int*)(houtg + (size_t)b0i * HBATCH);
        for (int i = lane; i < HBATCH; i += 64) dg[i] = s2[i];
    }
}

// ---------------- launch ----------------

extern "C" void kernel_launch(void* const* d_in, const int* in_sizes, int n_in,
                              void* d_out, int out_size, void* d_ws, size_t ws_size,
                              hipStream_t stream) {
    const float* x  = (const float*)d_in[0];
    const float* W0 = (const float*)d_in[1];
    const float* b0 = (const float*)d_in[2];
    const float* W1 = (const float*)d_in[3];
    const float* b1 = (const float*)d_in[4];
    const float* W2 = (const float*)d_in[5];
    const float* b2 = (const float*)d_in[6];
    float* out = (float*)d_out;
    char* ws = (char*)d_ws;

    f16* h0 = (f16*)(ws + OFF_H0);
    f16* h1 = (f16*)(ws + OFF_H1);
    f16* h2 = (f16*)(ws + OFF_H2);
    f16* w0s = (f16*)(ws + OFF_W0);
    f16* w1s = (f16*)(ws + OFF_W1);
    f16* w2s = (f16*)(ws + OFF_W2);
    float* biasws = (float*)(ws + OFF_BIAS);

    {
        long tot = (long)NB_TOT * HBATCH;
        k_prep_h0<<<(unsigned)((tot + 255) / 256), 256, 0, stream>>>(x, h0);
    }
    k_prep_w<<<(unsigned)(((long)49 * SLAB_F16S + 255) / 256), 256, 0, stream>>>(W0, w0s, 49, 5, 39);
    k_prep_w<<<(unsigned)(((long)127 * SLAB_F16S + 255) / 256), 256, 0, stream>>>(W1, w1s, 127, 13, 100);
    k_prep_w<<<(unsigned)(((long)127 * SLAB_F16S + 255) / 256), 256, 0, stream>>>(W2, w2s, 127, 13, 100);
    k_prep_bias<<<3, 256, 0, stream>>>(b0, b1, b2, biasws);

    // layer 0: hidden=x (hn=39, RUNS=5, 49 steps); direct = cur[100:200] -> out[:,0:100)
    k_layer<5><<<1024, 128, 0, stream>>>(h0, h0, w0s, biasws + 0, h1, out, 49, 100, 0);
    // layer 1: hn=100, RUNS=13, 127 steps; direct = cur[100:200] -> out[:,100:200)
    k_layer<13><<<1024, 128, 0, stream>>>(h0, h1, w1s, biasws + 208, h2, out, 127, 100, 100);
    // layer 2: hn=100, RUNS=13, 127 steps; direct = full cur -> out[:,200:400)
    k_layer<13><<<1024, 128, 0, stream>>>(h0, h2, w2s, biasws + 416, (f16*)nullptr, out, 127, 0, 200);
}